// Round 1
// 74.112 us; speedup vs baseline: 1.0723x; 1.0723x over previous
//
#include <hip/hip_runtime.h>
#include <math.h>

namespace {
constexpr int kB  = 16;
constexpr int kNV = 6890;
constexpr int kNF = 13776;
constexpr int kP  = kB / 2;          // 8 person-pairs
constexpr int kC  = 65536;           // collisions per pair
constexpr int kNB = 256;             // blocks: 32 per pair (XCD-pinned p = blk&7)
constexpr int kPasses = 8;           // 2048 collisions/block, 1/thread/pass
}

#define SIGMA_F  1e-4f
#define EPS_F    1e-9f
#define THRESH_F 2000.0f
#define WEIGHT_F 0.1f

// Persistent device state (self-resetting: last block zeroes it for the next
// graph replay — no host-side memset, no workspace dependency).
__device__ int      g_flag[kP]     = {};
__device__ unsigned g_count        = 0;
__device__ float    g_partials[kNB] = {};

// Exact reference-order cone distance field for one (receiver, intruder) pair.
__device__ __forceinline__ float cone_pair_loss(
    float3 r0, float3 r1, float3 r2, float3 i0, float3 i1, float3 i2) {
    float e1x = r1.x - r0.x, e1y = r1.y - r0.y, e1z = r1.z - r0.z;
    float e2x = r2.x - r0.x, e2y = r2.y - r0.y, e2z = r2.z - r0.z;
    float nx = e1y * e2z - e1z * e2y;
    float ny = e1z * e2x - e1x * e2z;
    float nz = e1x * e2y - e1y * e2x;
    float nn = sqrtf(nx * nx + ny * ny + nz * nz) + EPS_F;
    nx /= nn; ny /= nn; nz /= nn;
    float cx = (r0.x + r1.x + r2.x) / 3.0f;
    float cy = (r0.y + r1.y + r2.y) / 3.0f;
    float cz = (r0.z + r1.z + r2.z) / 3.0f;
    float r2m = 0.0f;
    {
        float dx = r0.x - cx, dy = r0.y - cy, dz = r0.z - cz;
        r2m = fmaxf(r2m, dx * dx + dy * dy + dz * dz);
        dx = r1.x - cx; dy = r1.y - cy; dz = r1.z - cz;
        r2m = fmaxf(r2m, dx * dx + dy * dy + dz * dz);
        dx = r2.x - cx; dy = r2.y - cy; dz = r2.z - cz;
        r2m = fmaxf(r2m, dx * dx + dy * dy + dz * dz);
    }
    float rad_eps = sqrtf(r2m) + EPS_F;
    float3 iv[3] = {i0, i1, i2};
    float acc = 0.0f;
#pragma unroll
    for (int k = 0; k < 3; ++k) {
        float dx = iv[k].x - cx, dy = iv[k].y - cy, dz = iv[k].z - cz;
        float d = dx * nx + dy * ny + dz * nz;
        float px = dx - d * nx, py = dy - d * ny, pz = dz - d * nz;
        float radial = sqrtf(px * px + py * py + pz * pz);
        float fa = fmaxf(-d / SIGMA_F, 0.0f);
        float fb = fmaxf(1.0f - radial / rad_eps, 0.0f);
        float fd = fa * fb;
        acc += fd * fd;
    }
    return acc;
}

// Direct gather + eval of one collision (branchless validity multiply so all
// scattered loads issue regardless of lane divergence).
__device__ __forceinline__ float eval_collision(
    int p, int2 idx,
    const float* __restrict__ verts, const int* __restrict__ faces,
    float t0x, float t0y, float t0z, float t1x, float t1y, float t1z) {
    int hi = (idx.x >= kNF) ? 1 : 0;
    int hr = (idx.y >= kNF) ? 1 : 0;
    const int* fi = faces + 3 * (idx.x - hi * kNF);
    const int* fr = faces + 3 * (idx.y - hr * kNF);
    int vi0 = fi[0], vi1 = fi[1], vi2 = fi[2];
    int vr0 = fr[0], vr1 = fr[1], vr2 = fr[2];
    size_t bi = (size_t)(2 * p + hi) * kNV;
    size_t br = (size_t)(2 * p + hr) * kNV;
    float tix = hi ? t1x : t0x, tiy = hi ? t1y : t0y, tiz = hi ? t1z : t0z;
    float trx = hr ? t1x : t0x, try_ = hr ? t1y : t0y, trz = hr ? t1z : t0z;
    const float* q;
    q = verts + (bi + vi0) * 3; float3 i0 = make_float3(q[0] + tix, q[1] + tiy, q[2] + tiz);
    q = verts + (bi + vi1) * 3; float3 i1 = make_float3(q[0] + tix, q[1] + tiy, q[2] + tiz);
    q = verts + (bi + vi2) * 3; float3 i2 = make_float3(q[0] + tix, q[1] + tiy, q[2] + tiz);
    q = verts + (br + vr0) * 3; float3 r0 = make_float3(q[0] + trx, q[1] + try_, q[2] + trz);
    q = verts + (br + vr1) * 3; float3 r1 = make_float3(q[0] + trx, q[1] + try_, q[2] + trz);
    q = verts + (br + vr2) * 3; float3 r2 = make_float3(q[0] + trx, q[1] + try_, q[2] + trz);
    float v = cone_pair_loss(r0, r1, r2, i0, i1, i2);
    return (idx.x != idx.y) ? v : 0.0f;
}

// Single fused kernel.
//
// EXACT early exit: every pair_loss term is >= 0, so any partial sum >= 2000
// proves pen[p] >= 2000 => keep[p] = 0 => the pair contributes exactly 0 to
// the loss. Blocks poll a per-pair advisory flag between passes and break.
// No block ever waits on another (no spin) => deadlock-free at any occupancy.
// The flag's final value is input-deterministic: a thread whose running sum
// would cross the threshold does so deterministically unless the flag is
// already set — so the output is bitwise reproducible.
__global__ void __launch_bounds__(256)
pen_fused(const int* __restrict__ coll,
          const float* __restrict__ verts,
          const float* __restrict__ trans,
          const int* __restrict__ faces,
          float* __restrict__ out) {
    const int blk  = blockIdx.x;
    const int p    = blk & 7;                      // XCD-pinned pair
    const int base = (blk >> 3) * (kPasses * 256); // this block's collision window
    const int2* cp = (const int2*)coll + (size_t)p * kC;

    const float t0x = trans[6 * p + 0], t0y = trans[6 * p + 1], t0z = trans[6 * p + 2];
    const float t1x = trans[6 * p + 3], t1y = trans[6 * p + 4], t1z = trans[6 * p + 5];

    __shared__ int   s_any[4];
    __shared__ int   s_stop;
    __shared__ float s_red[4];
    __shared__ float s_pen[kP];

    const int lane = threadIdx.x & 63;
    const int wid  = threadIdx.x >> 6;

    float acc = 0.0f;
    for (int s = 0; s < kPasses; ++s) {
        int2 idx = cp[base + s * 256 + threadIdx.x];
        acc += eval_collision(p, idx, verts, faces, t0x, t0y, t0z, t1x, t1y, t1z);

        // threshold check: any lane's running (non-negative) sum >= 2000?
        int ex = __any(acc >= THRESH_F) ? 1 : 0;
        if (lane == 0) s_any[wid] = ex;
        __syncthreads();
        if (threadIdx.x == 0) {
            int any = s_any[0] | s_any[1] | s_any[2] | s_any[3];
            int f = any;
            if (any) {
                __hip_atomic_store(&g_flag[p], 1, __ATOMIC_RELAXED,
                                   __HIP_MEMORY_SCOPE_AGENT);
            } else if (s + 1 < kPasses) {
                f = __hip_atomic_load(&g_flag[p], __ATOMIC_RELAXED,
                                      __HIP_MEMORY_SCOPE_AGENT);
            }
            s_stop = f;
        }
        __syncthreads();
        if (s_stop) break;   // pair provably discarded: remaining work is dead
    }

    // block partial (fixed order => deterministic when it matters)
#pragma unroll
    for (int off = 32; off > 0; off >>= 1)
        acc += __shfl_down(acc, off, 64);
    if (lane == 0) s_red[wid] = acc;
    __syncthreads();
    if (threadIdx.x == 0) {
        float partial = s_red[0] + s_red[1] + s_red[2] + s_red[3];
        __hip_atomic_store(&g_partials[blk], partial, __ATOMIC_RELEASE,
                           __HIP_MEMORY_SCOPE_AGENT);
        unsigned old = __hip_atomic_fetch_add(&g_count, 1u, __ATOMIC_ACQ_REL,
                                              __HIP_MEMORY_SCOPE_AGENT);
        s_stop = (old == (unsigned)(kNB - 1));
    }
    __syncthreads();
    if (!s_stop) return;

    // ---- last block: finalize + reset persistent state ----
    const int t = threadIdx.x;
    const int q = t >> 5;   // pair 0..7
    const int j = t & 31;   // its 32 partial slots
    float v = __hip_atomic_load(&g_partials[q + 8 * j], __ATOMIC_ACQUIRE,
                                __HIP_MEMORY_SCOPE_AGENT);
#pragma unroll
    for (int off = 16; off > 0; off >>= 1)
        v += __shfl_down(v, off, 32);
    if (j == 0) s_pen[q] = v;
    __syncthreads();
    if (t == 0) {
        float cnt = 0.0f, vals = 0.0f;
#pragma unroll
        for (int e = 0; e < kP; ++e) {
            int fl = __hip_atomic_load(&g_flag[e], __ATOMIC_RELAXED,
                                       __HIP_MEMORY_SCOPE_AGENT);
            float pq = s_pen[e];
            if (!fl && pq < THRESH_F) {   // NaN pen => excluded, matches jax
                cnt += 1.0f;
                vals += 1.0f / (1.0f + expf(-pq / THRESH_F)) - 0.5f;
            }
        }
        float loss = (cnt > 0.0f) ? (vals / fmaxf(cnt, 1.0f)) : 0.0f;
        out[0] = loss * WEIGHT_F;
        // reset for the next graph replay (stream-ordered => race-free)
#pragma unroll
        for (int e = 0; e < kP; ++e)
            __hip_atomic_store(&g_flag[e], 0, __ATOMIC_RELAXED,
                               __HIP_MEMORY_SCOPE_AGENT);
        __hip_atomic_store(&g_count, 0u, __ATOMIC_RELEASE,
                           __HIP_MEMORY_SCOPE_AGENT);
    }
}

extern "C" void kernel_launch(void* const* d_in, const int* in_sizes, int n_in,
                              void* d_out, int out_size, void* d_ws, size_t ws_size,
                              hipStream_t stream) {
    const float* verts = (const float*)d_in[0];
    const float* trans = (const float*)d_in[1];
    const int*   faces = (const int*)d_in[2];
    const int*   coll  = (const int*)d_in[3];
    (void)d_ws; (void)ws_size; (void)in_sizes; (void)n_in; (void)out_size;
    pen_fused<<<kNB, 256, 0, stream>>>(coll, verts, trans, faces, (float*)d_out);
}